// Round 15
// baseline (183.556 us; speedup 1.0000x reference)
//
#include <hip/hip_runtime.h>
#include <hip/hip_bf16.h>

// Kuramoto V2: B=8, N=2048, D=256, 50 steps.
// R15 = R14 (178us) with a denser build tile; step loop FROZEN (at its
// ~2.8us/step cross-XCD latency floor: sleep(1)==sleep(8) A/B ruled out
// poll contention).
//  (a) build_c_k: 128x128 triangular tiles (136 pairs/batch, 512 thr,
//      128KB LDS, 64 MFMA/wave) -- staged panel traffic halves (270->139MB),
//      4x MFMA per staged byte. Same k-order/swizzle/symmetric store =>
//      bit-identical C to R14.
//  (b) normalize_k, fused_steps_k: byte-identical to R14.
// Sync (R10, proven): msg u32 = stamp<<16|sin8<<8|cos8, relaxed agent
// atomics, parity dbuf, exact stamp match; no fences.

constexpr int B = 8;
constexpr int N = 2048;
constexpr int D = 256;
constexpr int STEPS = 50;
constexpr int ROWS = 64;            // C-rows per block (fused)
constexpr int BPB  = 32;            // blocks per batch (fused)
constexpr int TPB  = 512;           // threads per block (fused)
constexpr int NPAIRS = 136;         // 16*17/2 triangular 128-tile pairs
constexpr float DT = 0.01f;
constexpr float K_OVER_N = 1.0f / 2048.0f;
constexpr float TWO_PI_F = 6.2831854820251465f; // float(2*pi)

using bf16x8 = __attribute__((ext_vector_type(8))) short;
using f32x4  = __attribute__((ext_vector_type(4))) float;

static __device__ __forceinline__ unsigned short f2bf(float f) {
    union { float f; unsigned int i; } v; v.f = f;
    unsigned int x = v.i;
    x += 0x7fffu + ((x >> 16) & 1u);   // RNE
    return (unsigned short)(x >> 16);
}
static __device__ __forceinline__ unsigned char f2fp8(float f) {
    return (unsigned char)(__builtin_amdgcn_cvt_pk_fp8_f32(f, f, 0, false) & 0xff);
}

// ---------------- normalize: one wave per row of 256 floats -> bf16 -------
__global__ void normalize_k(const float* __restrict__ emb,
                            unsigned short* __restrict__ En) {
    const int row  = blockIdx.x * 4 + (threadIdx.x >> 6);
    const int lane = threadIdx.x & 63;
    const float4 v = *(const float4*)(emb + (size_t)row * D + lane * 4);
    float ss = v.x * v.x + v.y * v.y + v.z * v.z + v.w * v.w;
    #pragma unroll
    for (int k = 32; k >= 1; k >>= 1) ss += __shfl_xor(ss, k);
    const float inv = 1.0f / fmaxf(sqrtf(ss), 1e-12f);
    ushort4 o;
    o.x = f2bf(v.x * inv); o.y = f2bf(v.y * inv);
    o.z = f2bf(v.z * inv); o.w = f2bf(v.w * inv);
    *(ushort4*)(En + (size_t)row * D + lane * 4) = o;
}

// ---------------- build C = clip(En En^T, 0) -> fp8 row-major --------------
// Triangular 128x128 tiles: blockIdx.x = pair p -> (ti<=tj). 512 threads,
// 8 waves as 2(row)x4(col): wave = 64x32 output (4x2 frags of 16x16).
// Panels (128x256 bf16 = 64KB each) LDS-staged, 16B-unit XOR swizzle.
// Primary store (u32, bit-identical to R11/R14): Cb[j*N+i]; mirror byte
// stores Cb[i*N+j] for ti!=tj. Diagonal pair computes its full square.
__global__ __launch_bounds__(512) void build_c_k(const unsigned short* __restrict__ En,
                                                 unsigned char* __restrict__ C) {
    __shared__ unsigned char s_Ai[128 * 512];   // 64 KB, swizzled
    __shared__ unsigned char s_Aj[128 * 512];   // 64 KB, swizzled
    const int b = blockIdx.y;
    const int p = blockIdx.x;
    // decode triangular pair: p = tj*(tj+1)/2 + ti, ti <= tj
    int tj = (int)((sqrtf(8.f * (float)p + 1.f) - 1.f) * 0.5f);
    while ((tj + 1) * (tj + 2) / 2 <= p) ++tj;
    while (tj * (tj + 1) / 2 > p) --tj;
    const int ti = p - tj * (tj + 1) / 2;

    const unsigned short* Eb = En + (size_t)b * N * D;
    const int t = threadIdx.x;
    const int w = t >> 6;
    const int lane = t & 63;

    // ---- stage both panels (coalesced reads, swizzled writes) ----
    {
        const unsigned char* srcI = (const unsigned char*)(Eb + (size_t)ti * 128 * D);
        const unsigned char* srcJ = (const unsigned char*)(Eb + (size_t)tj * 128 * D);
        #pragma unroll
        for (int it = 0; it < 8; ++it) {
            const int L   = it * 512 + t;       // 16B-unit index, 0..4095
            const int row = L >> 5;             // 32 units (512B) per row
            const int u   = L & 31;
            const int doff = row * 512 + ((u * 16) ^ ((row & 7) << 4));
            const int goff = row * 512 + u * 16;
            *(uint4*)(s_Ai + doff) = *(const uint4*)(srcI + goff);
            *(uint4*)(s_Aj + doff) = *(const uint4*)(srcJ + goff);
        }
    }
    __syncthreads();

    const int i_off = (w >> 2) * 64;            // wave row offset
    const int j_off = (w & 3) * 32;             // wave col offset
    const int fr = lane & 15;
    const int fq = lane >> 4;                   // k-subgroup (8 elem = 16 B)

    f32x4 acc[4][2];
    #pragma unroll
    for (int m = 0; m < 4; ++m)
        #pragma unroll
        for (int n = 0; n < 2; ++n)
            acc[m][n] = (f32x4){0.f, 0.f, 0.f, 0.f};

    #pragma unroll
    for (int k0 = 0; k0 < 512; k0 += 64) {      // 64 B = 32 elements per step
        bf16x8 a[4], bv[2];
        #pragma unroll
        for (int m = 0; m < 4; ++m) {
            const int row = i_off + m * 16 + fr;
            a[m] = *(const bf16x8*)(s_Ai + row * 512 + ((k0 + fq * 16) ^ ((row & 7) << 4)));
        }
        #pragma unroll
        for (int n = 0; n < 2; ++n) {
            const int row = j_off + n * 16 + fr;
            bv[n] = *(const bf16x8*)(s_Aj + row * 512 + ((k0 + fq * 16) ^ ((row & 7) << 4)));
        }
        #pragma unroll
        for (int m = 0; m < 4; ++m)
            #pragma unroll
            for (int n = 0; n < 2; ++n)
                acc[m][n] = __builtin_amdgcn_mfma_f32_16x16x32_bf16(a[m], bv[n], acc[m][n], 0, 0, 0);
    }

    unsigned char* Cb = C + (size_t)b * N * N;
    const int i_base = ti * 128 + i_off;
    const int j_base = tj * 128 + j_off;
    const int orow = fq * 4;
    #pragma unroll
    for (int m = 0; m < 4; ++m)
        #pragma unroll
        for (int n = 0; n < 2; ++n) {
            int wpk = __builtin_amdgcn_cvt_pk_fp8_f32(fmaxf(acc[m][n][0], 0.f),
                                                      fmaxf(acc[m][n][1], 0.f), 0, false);
            wpk = __builtin_amdgcn_cvt_pk_fp8_f32(fmaxf(acc[m][n][2], 0.f),
                                                  fmaxf(acc[m][n][3], 0.f), wpk, true);
            const int j = j_base + n * 16 + fr;
            const int i = i_base + m * 16 + orow;
            *(unsigned int*)(Cb + (size_t)j * N + i) = (unsigned int)wpk;
            if (ti != tj) {                      // mirror: fills (row=i, col=j)
                #pragma unroll
                for (int r = 0; r < 4; ++r)
                    Cb[(size_t)(i + r) * N + j] =
                        (unsigned char)((wpk >> (8 * r)) & 0xff);
            }
        }
}

// ---------------- persistent 50-step kernel (R14, frozen) ------------------
__global__ __launch_bounds__(512, 2) void fused_steps_k(
        const unsigned char* __restrict__ C,
        const float* __restrict__ theta0,
        float* __restrict__ out,
        const float* __restrict__ omega,
        unsigned int* __restrict__ msg) {
    __shared__ unsigned char s_C[ROWS * 2048];     // 128 KB, swizzled
    __shared__ unsigned char s_tbl[2080 + 2048];   // cos | pad32 | sin
    __shared__ f32x4 s_acc[8][8];                  // [wave][g*2+col]

    const int rt = blockIdx.x;        // 0..31: rows rt*64..rt*64+63
    const int b  = blockIdx.y;
    const int t  = threadIdx.x;
    const int w = t >> 6, lane = t & 63;
    const int col = lane & 15, g = lane >> 4;
    const int grp = w >> 1, kh = w & 1;

    // ---- per-row register state (t < 64) + init publish (stamp 1) ----
    float th = 0.f, sth = 0.f, cth = 0.f, om = 0.f;
    if (t < ROWS) {
        th = theta0[(size_t)b * N + rt * ROWS + t];
        om = omega[rt * ROWS + t];
        sth = __sinf(th); cth = __cosf(th);
        const unsigned int m = (1u << 16) |
            ((unsigned int)f2fp8(sth) << 8) | (unsigned int)f2fp8(cth);
        __hip_atomic_store(&msg[(size_t)b * N + rt * ROWS + t], m,
                           __ATOMIC_RELAXED, __HIP_MEMORY_SCOPE_AGENT);
    }

    // ---- stage my 64 C-rows into LDS once, XOR-swizzle 16B units ----
    {
        const unsigned char* src = C + ((size_t)b * N + rt * ROWS) * N;
        #pragma unroll
        for (int it = 0; it < 16; ++it) {
            const int idx = it * TPB + t;        // 16B-unit index, 0..8191
            const int row = idx >> 7;            // 128 units per 2048B row
            const int o   = (idx & 127) * 16;
            const uint4 v = *(const uint4*)(src + (size_t)row * N + o);
            *(uint4*)(s_C + row * 2048 + (o ^ ((row & 7) << 4))) = v;
        }
    }

    const unsigned char* Abase = s_C + (grp * 16 + col) * 2048;
    const unsigned int sw = (unsigned)((col & 7) << 4);
    const int tblbase = (col == 1) ? 2080 : 0;    // col1 -> sin; else cos
    const int o0 = kh * 1024 + g * 8;
    const int r0 = t * 4;                         // 4 rows polled per thread

    for (int s = 0; s < STEPS; ++s) {
        // ---- consume: poll 4 payload dwords until stamp == s+1 ----
        const unsigned int* mb = msg + ((size_t)(s & 1) * B + b) * N + r0;
        const unsigned int tgt = (unsigned int)(s + 1);
        unsigned int g0, g1, g2, g3;
        for (;;) {
            g0 = __hip_atomic_load(mb + 0, __ATOMIC_RELAXED, __HIP_MEMORY_SCOPE_AGENT);
            g1 = __hip_atomic_load(mb + 1, __ATOMIC_RELAXED, __HIP_MEMORY_SCOPE_AGENT);
            g2 = __hip_atomic_load(mb + 2, __ATOMIC_RELAXED, __HIP_MEMORY_SCOPE_AGENT);
            g3 = __hip_atomic_load(mb + 3, __ATOMIC_RELAXED, __HIP_MEMORY_SCOPE_AGENT);
            if (((g0 >> 16) == tgt) & ((g1 >> 16) == tgt) &
                ((g2 >> 16) == tgt) & ((g3 >> 16) == tgt)) break;
            __builtin_amdgcn_s_sleep(8);
        }
        // unpack payload straight into LDS tables (4 cos + 4 sin bytes)
        const unsigned int uc = (g0 & 0xffu) | ((g1 & 0xffu) << 8) |
                                ((g2 & 0xffu) << 16) | ((g3 & 0xffu) << 24);
        const unsigned int us = ((g0 >> 8) & 0xffu) | (((g1 >> 8) & 0xffu) << 8) |
                                (((g2 >> 8) & 0xffu) << 16) | (((g3 >> 8) & 0xffu) << 24);
        *(unsigned int*)(s_tbl + r0) = uc;
        *(unsigned int*)(s_tbl + 2080 + r0) = us;
        __syncthreads();

        // ---- dual matvec via fp8 MFMA, A from swizzled LDS, 2-acc ILP ----
        f32x4 acc0 = {0.f, 0.f, 0.f, 0.f}, acc1 = {0.f, 0.f, 0.f, 0.f};
        #pragma unroll
        for (int u = 0; u < 32; u += 2) {
            const int oa = o0 + u * 32;
            const long a0 = *(const long*)(Abase + (oa ^ sw));
            const long a1 = *(const long*)(Abase + ((oa + 32) ^ sw));
            long b0 = *(const long*)(s_tbl + tblbase + oa);
            long b1 = *(const long*)(s_tbl + tblbase + oa + 32);
            b0 = (col < 2) ? b0 : 0L;
            b1 = (col < 2) ? b1 : 0L;
            acc0 = __builtin_amdgcn_mfma_f32_16x16x32_fp8_fp8(a0, b0, acc0, 0, 0, 0);
            acc1 = __builtin_amdgcn_mfma_f32_16x16x32_fp8_fp8(a1, b1, acc1, 0, 0, 0);
        }
        acc0 += acc1;
        if (col < 2) s_acc[w][g * 2 + col] = acc0;
        __syncthreads();

        // ---- finalize rows (64 writers, all in wave 0): publish FIRST ----
        if (t < ROWS) {
            const int gr = t >> 4;                   // row-group
            const int gg = ((t & 15) >> 2) * 2;      // s_acc slot base
            const int rr = t & 3;                    // reg within frag
            float S1 = 0.f, S2 = 0.f;
            #pragma unroll
            for (int h = 0; h < 2; ++h) {            // two K-halves
                S1 += s_acc[gr * 2 + h][gg + 0][rr];
                S2 += s_acc[gr * 2 + h][gg + 1][rr];
            }
            const float csum = sth * S1 - cth * S2;
            th = th + DT * (om + K_OVER_N * csum);
            if (th >= TWO_PI_F) th -= TWO_PI_F;      // exact (Sterbenz) == fmodf
            if (s < STEPS - 1) {
                sth = __sinf(th); cth = __cosf(th);
                const unsigned int m = ((unsigned int)(s + 2) << 16) |
                    ((unsigned int)f2fp8(sth) << 8) | (unsigned int)f2fp8(cth);
                __hip_atomic_store(
                    &msg[((size_t)((s + 1) & 1) * B + b) * N + rt * ROWS + t],
                    m, __ATOMIC_RELAXED, __HIP_MEMORY_SCOPE_AGENT);
            } else {
                out[(size_t)b * N + rt * ROWS + t] = th;
            }
        }
    }
}

extern "C" void kernel_launch(void* const* d_in, const int* in_sizes, int n_in,
                              void* d_out, int out_size, void* d_ws, size_t ws_size,
                              hipStream_t stream) {
    const float* theta0 = (const float*)d_in[0];  // [B,N]
    const float* emb    = (const float*)d_in[1];  // [B,N,D]
    const float* omega  = (const float*)d_in[2];  // [N]
    float* out = (float*)d_out;                   // [B,N]

    // workspace layout (~42 MiB)
    unsigned short* En = (unsigned short*)d_ws;                    // B*N*D bf16
    unsigned char*  C  = (unsigned char*)(En + (size_t)B * N * D); // B*N*N fp8
    unsigned int*  msg = (unsigned int*)(C + (size_t)B * N * N);   // 2*B*N u32

    normalize_k<<<B * N / 4, 256, 0, stream>>>(emb, En);

    build_c_k<<<dim3(NPAIRS, B), 512, 0, stream>>>(En, C);

    fused_steps_k<<<dim3(BPB, B), TPB, 0, stream>>>(C, theta0, out, omega, msg);
}

// Round 16
// 168.554 us; speedup vs baseline: 1.0890x; 1.0890x over previous
//
#include <hip/hip_runtime.h>
#include <hip/hip_bf16.h>

// Kuramoto V2: B=8, N=2048, D=256, 50 steps.
// R16 = R14 build (64^2 triangular, 2 blocks/CU -- R15's 128^2 regressed) +
// step loop with REGISTER-RESIDENT A-operands:
//   R12/R13 root cause found: __launch_bounds__(512,2) = 128-VGPR budget
//   forced rematerialization. Now (512,1) => 256-VGPR budget; each thread's
//   32 loop-invariant A-longs (64 VGPR) load once from staged LDS; the
//   per-step MFMA loop has no A-side ds_read and no swizzle math.
// Sync (R10, proven, frozen): msg u32 = stamp<<16|sin8<<8|cos8, relaxed
// agent atomics, parity dbuf, exact stamp match; no fences. ~2.8us/step.

constexpr int B = 8;
constexpr int N = 2048;
constexpr int D = 256;
constexpr int STEPS = 50;
constexpr int ROWS = 64;            // C-rows per block (fused)
constexpr int BPB  = 32;            // blocks per batch (fused)
constexpr int TPB  = 512;           // threads per block (fused)
constexpr int NPAIRS = 528;         // 32*33/2 triangular 64-tile pairs
constexpr float DT = 0.01f;
constexpr float K_OVER_N = 1.0f / 2048.0f;
constexpr float TWO_PI_F = 6.2831854820251465f; // float(2*pi)

using bf16x8 = __attribute__((ext_vector_type(8))) short;
using f32x4  = __attribute__((ext_vector_type(4))) float;

static __device__ __forceinline__ unsigned short f2bf(float f) {
    union { float f; unsigned int i; } v; v.f = f;
    unsigned int x = v.i;
    x += 0x7fffu + ((x >> 16) & 1u);   // RNE
    return (unsigned short)(x >> 16);
}
static __device__ __forceinline__ unsigned char f2fp8(float f) {
    return (unsigned char)(__builtin_amdgcn_cvt_pk_fp8_f32(f, f, 0, false) & 0xff);
}

// ---------------- normalize: one wave per row of 256 floats -> bf16 -------
__global__ void normalize_k(const float* __restrict__ emb,
                            unsigned short* __restrict__ En) {
    const int row  = blockIdx.x * 4 + (threadIdx.x >> 6);
    const int lane = threadIdx.x & 63;
    const float4 v = *(const float4*)(emb + (size_t)row * D + lane * 4);
    float ss = v.x * v.x + v.y * v.y + v.z * v.z + v.w * v.w;
    #pragma unroll
    for (int k = 32; k >= 1; k >>= 1) ss += __shfl_xor(ss, k);
    const float inv = 1.0f / fmaxf(sqrtf(ss), 1e-12f);
    ushort4 o;
    o.x = f2bf(v.x * inv); o.y = f2bf(v.y * inv);
    o.z = f2bf(v.z * inv); o.w = f2bf(v.w * inv);
    *(ushort4*)(En + (size_t)row * D + lane * 4) = o;
}

// ---------------- build C = clip(En En^T, 0) -> fp8 row-major (R14) --------
__global__ __launch_bounds__(256) void build_c_k(const unsigned short* __restrict__ En,
                                                 unsigned char* __restrict__ C) {
    __shared__ unsigned char s_Ai[64 * 512];   // 32 KB, swizzled
    __shared__ unsigned char s_Aj[64 * 512];   // 32 KB, swizzled
    const int b = blockIdx.y;
    const int p = blockIdx.x;
    // decode triangular pair: p = tj*(tj+1)/2 + ti, ti <= tj
    int tj = (int)((sqrtf(8.f * (float)p + 1.f) - 1.f) * 0.5f);
    while ((tj + 1) * (tj + 2) / 2 <= p) ++tj;
    while (tj * (tj + 1) / 2 > p) --tj;
    const int ti = p - tj * (tj + 1) / 2;

    const unsigned short* Eb = En + (size_t)b * N * D;
    const int t = threadIdx.x;
    const int wid  = t >> 6;
    const int lane = t & 63;

    // ---- stage both panels (coalesced reads, swizzled writes) ----
    {
        const unsigned char* srcI = (const unsigned char*)(Eb + (size_t)ti * 64 * D);
        const unsigned char* srcJ = (const unsigned char*)(Eb + (size_t)tj * 64 * D);
        #pragma unroll
        for (int it = 0; it < 8; ++it) {
            const int L   = it * 256 + t;       // 16B-unit index, 0..2047
            const int row = L >> 5;             // 32 units (512B) per row
            const int u   = L & 31;
            const int doff = row * 512 + ((u * 16) ^ ((row & 7) << 4));
            const int goff = row * 512 + u * 16;
            *(uint4*)(s_Ai + doff) = *(const uint4*)(srcI + goff);
            *(uint4*)(s_Aj + doff) = *(const uint4*)(srcJ + goff);
        }
    }
    __syncthreads();

    const int i_off = (wid >> 1) * 32;
    const int j_off = (wid & 1) * 32;
    const int fr = lane & 15;
    const int fq = lane >> 4;                   // k-subgroup (8 elem = 16 B)

    f32x4 acc[2][2];
    #pragma unroll
    for (int m = 0; m < 2; ++m)
        #pragma unroll
        for (int n = 0; n < 2; ++n)
            acc[m][n] = (f32x4){0.f, 0.f, 0.f, 0.f};

    #pragma unroll
    for (int k0 = 0; k0 < 512; k0 += 64) {      // 64 B = 32 elements per step
        bf16x8 a[2], bv[2];
        #pragma unroll
        for (int m = 0; m < 2; ++m) {
            const int row = i_off + m * 16 + fr;
            a[m] = *(const bf16x8*)(s_Ai + row * 512 + ((k0 + fq * 16) ^ ((row & 7) << 4)));
        }
        #pragma unroll
        for (int n = 0; n < 2; ++n) {
            const int row = j_off + n * 16 + fr;
            bv[n] = *(const bf16x8*)(s_Aj + row * 512 + ((k0 + fq * 16) ^ ((row & 7) << 4)));
        }
        #pragma unroll
        for (int m = 0; m < 2; ++m)
            #pragma unroll
            for (int n = 0; n < 2; ++n)
                acc[m][n] = __builtin_amdgcn_mfma_f32_16x16x32_bf16(a[m], bv[n], acc[m][n], 0, 0, 0);
    }

    unsigned char* Cb = C + (size_t)b * N * N;
    const int i_base = ti * 64 + i_off;
    const int j_base = tj * 64 + j_off;
    const int orow = fq * 4;
    #pragma unroll
    for (int m = 0; m < 2; ++m)
        #pragma unroll
        for (int n = 0; n < 2; ++n) {
            int wpk = __builtin_amdgcn_cvt_pk_fp8_f32(fmaxf(acc[m][n][0], 0.f),
                                                      fmaxf(acc[m][n][1], 0.f), 0, false);
            wpk = __builtin_amdgcn_cvt_pk_fp8_f32(fmaxf(acc[m][n][2], 0.f),
                                                  fmaxf(acc[m][n][3], 0.f), wpk, true);
            const int j = j_base + n * 16 + fr;
            const int i = i_base + m * 16 + orow;
            *(unsigned int*)(Cb + (size_t)j * N + i) = (unsigned int)wpk;
            if (ti != tj) {                      // mirror: fills (row=i, col=j)
                #pragma unroll
                for (int r = 0; r < 4; ++r)
                    Cb[(size_t)(i + r) * N + j] =
                        (unsigned char)((wpk >> (8 * r)) & 0xff);
            }
        }
}

// ---------------- persistent 50-step kernel --------------------------------
// launch_bounds (512,1): 256-VGPR budget so areg[32] (64 VGPR) stays
// register-resident. Grid = 256 blocks = 1/CU, so min-waves=1 costs nothing.
__global__ __launch_bounds__(512, 1) void fused_steps_k(
        const unsigned char* __restrict__ C,
        const float* __restrict__ theta0,
        float* __restrict__ out,
        const float* __restrict__ omega,
        unsigned int* __restrict__ msg) {
    __shared__ unsigned char s_C[ROWS * 2048];     // 128 KB, swizzled
    __shared__ unsigned char s_tbl[2080 + 2048];   // cos | pad32 | sin
    __shared__ f32x4 s_acc[8][8];                  // [wave][g*2+col]

    const int rt = blockIdx.x;        // 0..31: rows rt*64..rt*64+63
    const int b  = blockIdx.y;
    const int t  = threadIdx.x;
    const int w = t >> 6, lane = t & 63;
    const int col = lane & 15, g = lane >> 4;
    const int grp = w >> 1, kh = w & 1;

    // ---- per-row register state (t < 64) + init publish (stamp 1) ----
    float th = 0.f, sth = 0.f, cth = 0.f, om = 0.f;
    if (t < ROWS) {
        th = theta0[(size_t)b * N + rt * ROWS + t];
        om = omega[rt * ROWS + t];
        sth = __sinf(th); cth = __cosf(th);
        const unsigned int m = (1u << 16) |
            ((unsigned int)f2fp8(sth) << 8) | (unsigned int)f2fp8(cth);
        __hip_atomic_store(&msg[(size_t)b * N + rt * ROWS + t], m,
                           __ATOMIC_RELAXED, __HIP_MEMORY_SCOPE_AGENT);
    }

    // ---- stage my 64 C-rows into LDS once (coalesced), XOR-swizzled ----
    {
        const unsigned char* src = C + ((size_t)b * N + rt * ROWS) * N;
        #pragma unroll
        for (int it = 0; it < 16; ++it) {
            const int idx = it * TPB + t;        // 16B-unit index, 0..8191
            const int row = idx >> 7;            // 128 units per 2048B row
            const int o   = (idx & 127) * 16;
            const uint4 v = *(const uint4*)(src + (size_t)row * N + o);
            *(uint4*)(s_C + row * 2048 + (o ^ ((row & 7) << 4))) = v;
        }
    }
    __syncthreads();

    const unsigned char* Abase = s_C + (grp * 16 + col) * 2048;
    const unsigned int sw = (unsigned)((col & 7) << 4);
    const int tblbase = (col == 1) ? 2080 : 0;    // col1 -> sin; else cos
    const int o0 = kh * 1024 + g * 8;
    const int r0 = t * 4;                         // 4 rows polled per thread

    // ---- hoist loop-invariant A-operands into registers (64 VGPR) ----
    long areg[32];
    #pragma unroll
    for (int u = 0; u < 32; ++u)
        areg[u] = *(const long*)(Abase + ((o0 + u * 32) ^ sw));
    const long bmask = (col < 2) ? -1L : 0L;

    for (int s = 0; s < STEPS; ++s) {
        // ---- consume: poll 4 payload dwords until stamp == s+1 ----
        const unsigned int* mb = msg + ((size_t)(s & 1) * B + b) * N + r0;
        const unsigned int tgt = (unsigned int)(s + 1);
        unsigned int g0, g1, g2, g3;
        for (;;) {
            g0 = __hip_atomic_load(mb + 0, __ATOMIC_RELAXED, __HIP_MEMORY_SCOPE_AGENT);
            g1 = __hip_atomic_load(mb + 1, __ATOMIC_RELAXED, __HIP_MEMORY_SCOPE_AGENT);
            g2 = __hip_atomic_load(mb + 2, __ATOMIC_RELAXED, __HIP_MEMORY_SCOPE_AGENT);
            g3 = __hip_atomic_load(mb + 3, __ATOMIC_RELAXED, __HIP_MEMORY_SCOPE_AGENT);
            if (((g0 >> 16) == tgt) & ((g1 >> 16) == tgt) &
                ((g2 >> 16) == tgt) & ((g3 >> 16) == tgt)) break;
            __builtin_amdgcn_s_sleep(8);
        }
        // unpack payload straight into LDS tables (4 cos + 4 sin bytes)
        const unsigned int uc = (g0 & 0xffu) | ((g1 & 0xffu) << 8) |
                                ((g2 & 0xffu) << 16) | ((g3 & 0xffu) << 24);
        const unsigned int us = ((g0 >> 8) & 0xffu) | (((g1 >> 8) & 0xffu) << 8) |
                                (((g2 >> 8) & 0xffu) << 16) | (((g3 >> 8) & 0xffu) << 24);
        *(unsigned int*)(s_tbl + r0) = uc;
        *(unsigned int*)(s_tbl + 2080 + r0) = us;
        __syncthreads();

        // ---- dual matvec: A from registers, B from LDS tables ----
        f32x4 acc0 = {0.f, 0.f, 0.f, 0.f}, acc1 = {0.f, 0.f, 0.f, 0.f};
        #pragma unroll
        for (int u = 0; u < 32; u += 2) {
            const int oa = o0 + u * 32;
            const long b0 = *(const long*)(s_tbl + tblbase + oa) & bmask;
            const long b1 = *(const long*)(s_tbl + tblbase + oa + 32) & bmask;
            acc0 = __builtin_amdgcn_mfma_f32_16x16x32_fp8_fp8(areg[u], b0, acc0, 0, 0, 0);
            acc1 = __builtin_amdgcn_mfma_f32_16x16x32_fp8_fp8(areg[u + 1], b1, acc1, 0, 0, 0);
        }
        acc0 += acc1;
        if (col < 2) s_acc[w][g * 2 + col] = acc0;
        __syncthreads();

        // ---- finalize rows (64 writers, all in wave 0): publish FIRST ----
        if (t < ROWS) {
            const int gr = t >> 4;                   // row-group
            const int gg = ((t & 15) >> 2) * 2;      // s_acc slot base
            const int rr = t & 3;                    // reg within frag
            float S1 = 0.f, S2 = 0.f;
            #pragma unroll
            for (int h = 0; h < 2; ++h) {            // two K-halves
                S1 += s_acc[gr * 2 + h][gg + 0][rr];
                S2 += s_acc[gr * 2 + h][gg + 1][rr];
            }
            const float csum = sth * S1 - cth * S2;
            th = th + DT * (om + K_OVER_N * csum);
            if (th >= TWO_PI_F) th -= TWO_PI_F;      // exact (Sterbenz) == fmodf
            if (s < STEPS - 1) {
                sth = __sinf(th); cth = __cosf(th);
                const unsigned int m = ((unsigned int)(s + 2) << 16) |
                    ((unsigned int)f2fp8(sth) << 8) | (unsigned int)f2fp8(cth);
                __hip_atomic_store(
                    &msg[((size_t)((s + 1) & 1) * B + b) * N + rt * ROWS + t],
                    m, __ATOMIC_RELAXED, __HIP_MEMORY_SCOPE_AGENT);
            } else {
                out[(size_t)b * N + rt * ROWS + t] = th;
            }
        }
    }
}

extern "C" void kernel_launch(void* const* d_in, const int* in_sizes, int n_in,
                              void* d_out, int out_size, void* d_ws, size_t ws_size,
                              hipStream_t stream) {
    const float* theta0 = (const float*)d_in[0];  // [B,N]
    const float* emb    = (const float*)d_in[1];  // [B,N,D]
    const float* omega  = (const float*)d_in[2];  // [N]
    float* out = (float*)d_out;                   // [B,N]

    // workspace layout (~42 MiB)
    unsigned short* En = (unsigned short*)d_ws;                    // B*N*D bf16
    unsigned char*  C  = (unsigned char*)(En + (size_t)B * N * D); // B*N*N fp8
    unsigned int*  msg = (unsigned int*)(C + (size_t)B * N * N);   // 2*B*N u32

    normalize_k<<<B * N / 4, 256, 0, stream>>>(emb, En);

    build_c_k<<<dim3(NPAIRS, B), 256, 0, stream>>>(En, C);

    fused_steps_k<<<dim3(BPB, B), TPB, 0, stream>>>(C, theta0, out, omega, msg);
}